// Round 4
// baseline (1574.938 us; speedup 1.0000x reference)
//
#include <hip/hip_runtime.h>
#include <hip/hip_cooperative_groups.h>

namespace cg = cooperative_groups;

#define POOL_SHIFT 2
#define GRID_DIM 64
#define NUM_CELLS 4096
#define NCH 64
#define BATCH 64
#define NSEG (BATCH * NUM_CELLS)   // 262,144 cells
#define CHUNKS 1024                // NSEG / 256
#define RANK_BITS 14
#define RANK_MASK ((1u << RANK_BITS) - 1u)

typedef float vf4 __attribute__((ext_vector_type(4)));

// One cooperative kernel, phases separated by grid.sync():
// P0 zero counts | P1 histogram+cellrank | P2a chunk scans | P2b base scan
// P2c add base | P3 reorder | P4 gather (wave per cell)
__global__ __launch_bounds__(256, 8) void fused_kernel(
    const float* __restrict__ x, const int* __restrict__ pos,
    const int* __restrict__ batch, float* __restrict__ out,
    unsigned int* __restrict__ counts, unsigned int* __restrict__ offsets,
    unsigned int* __restrict__ blocksum, unsigned int* __restrict__ blockbase,
    unsigned int* __restrict__ cellrank, unsigned int* __restrict__ order,
    int n)
{
    cg::grid_group grid = cg::this_grid();
    const int t = threadIdx.x;
    const int T = (int)(gridDim.x * blockDim.x);
    const int gtid = (int)(blockIdx.x * blockDim.x + t);
    const int lane = t & 63;
    const int w = t >> 6;
    __shared__ unsigned int wsum[4];

    // ---- P0: zero counts (absorbs the old hipMemsetAsync dispatch) ----
    for (int i = gtid; i < NSEG; i += T) counts[i] = 0u;
    grid.sync();

    // ---- P1: histogram + packed (cell,rank) ----
    for (int p = gtid; p < n; p += T) {
        long long pr = __builtin_nontemporal_load((const long long*)pos + p);
        int px = (int)pr;              // pos[p][0]
        int py = (int)(pr >> 32);      // pos[p][1]
        int b  = __builtin_nontemporal_load(&batch[p]);
        int c  = b * NUM_CELLS + (px >> POOL_SHIFT) * GRID_DIM + (py >> POOL_SHIFT);
        unsigned int r = atomicAdd(&counts[c], 1u);
        __builtin_nontemporal_store(((unsigned int)c << RANK_BITS) | r, &cellrank[p]);
    }
    grid.sync();

    // ---- P2a: per-256-chunk exclusive scan (no base yet) + chunk totals ----
    for (int b = blockIdx.x; b < CHUNKS; b += (int)gridDim.x) {
        unsigned int own = counts[b * 256 + t];
        unsigned int v = own;
        #pragma unroll
        for (int off = 1; off < 64; off <<= 1) {
            unsigned int u = __shfl_up((int)v, off, 64);
            if (lane >= off) v += u;
        }
        if (lane == 63) wsum[w] = v;
        __syncthreads();
        unsigned int base = 0;
        for (int i = 0; i < w; ++i) base += wsum[i];
        offsets[b * 256 + t] = v + base - own;   // exclusive within chunk
        if (t == 255) blocksum[b] = v + base;    // chunk total
        __syncthreads();                         // wsum reuse across b-loop
    }
    grid.sync();

    // ---- P2b: block 0 scans the 1024 chunk totals -> exclusive bases ----
    if (blockIdx.x == 0) {
        unsigned int v0 = blocksum[t * 4 + 0], v1 = blocksum[t * 4 + 1];
        unsigned int v2 = blocksum[t * 4 + 2], v3 = blocksum[t * 4 + 3];
        unsigned int s0 = v0, s1 = s0 + v1, s2 = s1 + v2, tot = s2 + v3;
        unsigned int v = tot;
        #pragma unroll
        for (int off = 1; off < 64; off <<= 1) {
            unsigned int u = __shfl_up((int)v, off, 64);
            if (lane >= off) v += u;
        }
        if (lane == 63) wsum[w] = v;
        __syncthreads();
        unsigned int base = 0;
        for (int i = 0; i < w; ++i) base += wsum[i];
        unsigned int ex = v + base - tot;        // exclusive across threads
        blockbase[t * 4 + 0] = ex;
        blockbase[t * 4 + 1] = ex + s0;
        blockbase[t * 4 + 2] = ex + s1;
        blockbase[t * 4 + 3] = ex + s2;
    }
    grid.sync();

    // ---- P2c: add chunk base -> global exclusive offsets ----
    for (int i = gtid; i < NSEG; i += T) offsets[i] += blockbase[i >> 8];
    if (gtid == 0) offsets[NSEG] = (unsigned int)n;
    grid.sync();

    // ---- P3: scatter point ids into cell-sorted order ----
    for (int p = gtid; p < n; p += T) {
        unsigned int u = __builtin_nontemporal_load(&cellrank[p]);
        order[offsets[u >> RANK_BITS] + (u & RANK_MASK)] = (unsigned int)p;
    }
    grid.sync();

    // ---- P4: gather, one wave per cell, float4 row-group loads ----
    const int rg = lane >> 4;       // row group 0..3
    const int cgch = lane & 15;     // channel group
    const int gw = gtid >> 6;
    const int nw = T >> 6;
    const float NEG_INF = -__builtin_inff();

    for (int cell = gw; cell < NSEG; cell += nw) {
        unsigned int s = offsets[cell];
        unsigned int e = offsets[cell + 1];
        size_t ob = (size_t)cell * NCH + (size_t)cgch * 4;
        if (s == e) {
            if (lane < 16) {
                vf4 z = (vf4)(0.0f);
                __builtin_nontemporal_store(z, (vf4*)&out[ob]);
            }
            continue;
        }
        vf4 acc = (vf4)(NEG_INF);
        for (unsigned int base = s; base < e; base += 64) {
            unsigned int rem = e - base;                 // wave-uniform
            unsigned int cnt = rem < 64u ? rem : 64u;
            unsigned int li = (unsigned int)lane < cnt ? (unsigned int)lane : cnt - 1u;
            unsigned int myp = order[base + li];         // coalesced id load

            for (unsigned int j = 0; j < cnt; j += 4) {  // uniform trip count
                unsigned int rr = j + (unsigned int)rg;
                if (rr >= cnt) rr = cnt - 1u;            // clamp (max-idempotent)
                unsigned int p = (unsigned int)__shfl((int)myp, (int)rr, 64);
                vf4 v = __builtin_nontemporal_load(
                    (const vf4*)&x[(size_t)p * NCH + (size_t)cgch * 4]);
                acc.x = fmaxf(acc.x, v.x);
                acc.y = fmaxf(acc.y, v.y);
                acc.z = fmaxf(acc.z, v.z);
                acc.w = fmaxf(acc.w, v.w);
            }
        }
        #pragma unroll
        for (int off = 16; off < 64; off <<= 1) {
            acc.x = fmaxf(acc.x, __shfl_xor(acc.x, off, 64));
            acc.y = fmaxf(acc.y, __shfl_xor(acc.y, off, 64));
            acc.z = fmaxf(acc.z, __shfl_xor(acc.z, off, 64));
            acc.w = fmaxf(acc.w, __shfl_xor(acc.w, off, 64));
        }
        if (lane < 16) {
            __builtin_nontemporal_store(acc, (vf4*)&out[ob]);
        }
    }
}

extern "C" void kernel_launch(void* const* d_in, const int* in_sizes, int n_in,
                              void* d_out, int out_size, void* d_ws, size_t ws_size,
                              hipStream_t stream) {
    const float* x   = (const float*)d_in[0];
    const int* pos   = (const int*)d_in[1];
    const int* batch = (const int*)d_in[2];
    float* out = (float*)d_out;
    int n = in_sizes[2];

    // workspace layout (~10 MB)
    unsigned int* counts    = (unsigned int*)d_ws;          // NSEG
    unsigned int* offsets   = counts + NSEG;                // NSEG + 1
    unsigned int* blocksum  = offsets + NSEG + 1;           // 1024
    unsigned int* blockbase = blocksum + 1024;              // 1024
    unsigned int* cellrank  = blockbase + 1024;             // N
    unsigned int* order     = cellrank + n;                 // N

    // co-resident grid size (cached): 256 CUs * blocks/CU from occupancy
    static int g_blocks = 0;
    if (g_blocks == 0) {
        int nb = 0;
        (void)hipOccupancyMaxActiveBlocksPerMultiprocessor(&nb, fused_kernel, 256, 0);
        if (nb < 1) nb = 1;
        g_blocks = nb * 256;
        if (g_blocks > 2048) g_blocks = 2048;   // 8192 waves = device residency cap
    }

    void* args[] = {(void*)&x, (void*)&pos, (void*)&batch, (void*)&out,
                    (void*)&counts, (void*)&offsets, (void*)&blocksum,
                    (void*)&blockbase, (void*)&cellrank, (void*)&order, (void*)&n};
    (void)hipLaunchCooperativeKernel((const void*)fused_kernel, dim3(g_blocks),
                                     dim3(256), args, 0, stream);
}

// Round 5
// 433.931 us; speedup vs baseline: 3.6295x; 3.6295x over previous
//
#include <hip/hip_runtime.h>

#define POOL_SHIFT 2
#define GRID_DIM 64
#define NUM_CELLS 4096
#define NCH 64
#define BATCH 64
#define NSEG (BATCH * NUM_CELLS)   // 262,144 cells
#define SCAN_BLOCKS 1024           // NSEG / 256
#define RANK_BITS 14
#define RANK_MASK ((1u << RANK_BITS) - 1u)

typedef float vf4 __attribute__((ext_vector_type(4)));

// ---- K1: histogram + packed (cell,rank) per point ----
__global__ __launch_bounds__(256) void count_kernel(
    const int* __restrict__ pos, const int* __restrict__ batch,
    unsigned int* __restrict__ counts, unsigned int* __restrict__ cellrank, int n) {
    int stride = gridDim.x * blockDim.x;
    for (int p = blockIdx.x * blockDim.x + threadIdx.x; p < n; p += stride) {
        long long t = __builtin_nontemporal_load((const long long*)pos + p);
        int px = (int)t;               // pos[p][0]
        int py = (int)(t >> 32);       // pos[p][1]
        int b  = __builtin_nontemporal_load(&batch[p]);
        int c  = b * NUM_CELLS + (px >> POOL_SHIFT) * GRID_DIM + (py >> POOL_SHIFT);
        unsigned int r = atomicAdd(&counts[c], 1u);
        __builtin_nontemporal_store(((unsigned int)c << RANK_BITS) | r, &cellrank[p]);
    }
}

// ---- K2a: per-256-chunk sums (wave shuffle reduce, 1 barrier) ----
__global__ __launch_bounds__(256) void reduce_kernel(
    const unsigned int* __restrict__ counts, unsigned int* __restrict__ blocksum) {
    __shared__ unsigned int ws[4];
    int t = threadIdx.x;
    unsigned int v = counts[blockIdx.x * 256 + t];
    #pragma unroll
    for (int off = 1; off < 64; off <<= 1) v += __shfl_xor((int)v, off, 64);
    if ((t & 63) == 0) ws[t >> 6] = v;
    __syncthreads();
    if (t == 0) blocksum[blockIdx.x] = ws[0] + ws[1] + ws[2] + ws[3];
}

// ---- K2b: exclusive scan of the 1024 chunk sums (single block, shfl scan) ----
__global__ __launch_bounds__(1024) void scanblock_kernel(
    const unsigned int* __restrict__ blocksum, unsigned int* __restrict__ blockbase) {
    __shared__ unsigned int wsum[16];
    int t = threadIdx.x, lane = t & 63, w = t >> 6;
    unsigned int own = blocksum[t];
    unsigned int v = own;
    #pragma unroll
    for (int off = 1; off < 64; off <<= 1) {
        unsigned int u = __shfl_up((int)v, off, 64);
        if (lane >= off) v += u;
    }
    if (lane == 63) wsum[w] = v;
    __syncthreads();
    unsigned int base = 0;
    for (int i = 0; i < w; ++i) base += wsum[i];
    blockbase[t] = v + base - own;   // exclusive
}

// ---- K2c: per-chunk exclusive scan + base -> global offsets ----
__global__ __launch_bounds__(256) void offsets_kernel(
    const unsigned int* __restrict__ counts, const unsigned int* __restrict__ blockbase,
    unsigned int* __restrict__ offsets, int n) {
    __shared__ unsigned int wsum[4];
    int t = threadIdx.x, b = blockIdx.x, lane = t & 63, w = t >> 6;
    unsigned int own = counts[b * 256 + t];
    unsigned int v = own;
    #pragma unroll
    for (int off = 1; off < 64; off <<= 1) {
        unsigned int u = __shfl_up((int)v, off, 64);
        if (lane >= off) v += u;
    }
    if (lane == 63) wsum[w] = v;
    __syncthreads();
    unsigned int base = blockbase[b];
    for (int i = 0; i < w; ++i) base += wsum[i];
    unsigned int incl = v + base;
    offsets[b * 256 + t] = incl - own;               // exclusive
    if (b == SCAN_BLOCKS - 1 && t == 255) offsets[NSEG] = incl;  // == n
}

// ---- K3: scatter point ids into cell-sorted order ----
__global__ __launch_bounds__(256) void reorder_kernel(
    const unsigned int* __restrict__ cellrank,
    const unsigned int* __restrict__ offsets, unsigned int* __restrict__ order, int n) {
    int stride = gridDim.x * blockDim.x;
    for (int p = blockIdx.x * blockDim.x + threadIdx.x; p < n; p += stride) {
        unsigned int u = __builtin_nontemporal_load(&cellrank[p]);
        unsigned int c = u >> RANK_BITS;
        order[offsets[c] + (u & RANK_MASK)] = (unsigned int)p;
    }
}

// ---- K4: one 16-lane group per cell, 4 cells per wave ----
// Group = 16 lanes x float4 = all 64 channels of one cell.
// Point ids are group-uniform scalar loads (no shuffles); 4 independent
// row loads in flight per group (16 per wave); adjacent cells -> the
// final store is one contiguous 1 KB wave store.
__global__ __launch_bounds__(256) void gather_kernel(
    const float* __restrict__ x, const unsigned int* __restrict__ offsets,
    const unsigned int* __restrict__ order, float* __restrict__ out) {
    int t = threadIdx.x;
    int lane = t & 63;
    int sub = lane >> 4;       // which of the wave's 4 cells
    int cg  = lane & 15;       // channel quad: channels cg*4 .. cg*4+3
    int gw = (int)((blockIdx.x * blockDim.x + t) >> 6);
    int nw = (int)((gridDim.x * blockDim.x) >> 6);
    const float NEG_INF = -__builtin_inff();

    for (int g = gw; g < NSEG / 4; g += nw) {
        int c = g * 4 + sub;
        unsigned int s = offsets[c];       // group-uniform
        unsigned int e = offsets[c + 1];
        unsigned int cnt = e - s;
        vf4 acc = (vf4)(NEG_INF);

        unsigned int k = 0;
        for (; k + 4 <= cnt; k += 4) {     // 4 rows in flight per group
            unsigned int p0 = order[s + k];
            unsigned int p1 = order[s + k + 1];
            unsigned int p2 = order[s + k + 2];
            unsigned int p3 = order[s + k + 3];
            vf4 v0 = *(const vf4*)&x[(size_t)p0 * NCH + (size_t)cg * 4];
            vf4 v1 = *(const vf4*)&x[(size_t)p1 * NCH + (size_t)cg * 4];
            vf4 v2 = *(const vf4*)&x[(size_t)p2 * NCH + (size_t)cg * 4];
            vf4 v3 = *(const vf4*)&x[(size_t)p3 * NCH + (size_t)cg * 4];
            acc.x = fmaxf(fmaxf(fmaxf(acc.x, v0.x), fmaxf(v1.x, v2.x)), v3.x);
            acc.y = fmaxf(fmaxf(fmaxf(acc.y, v0.y), fmaxf(v1.y, v2.y)), v3.y);
            acc.z = fmaxf(fmaxf(fmaxf(acc.z, v0.z), fmaxf(v1.z, v2.z)), v3.z);
            acc.w = fmaxf(fmaxf(fmaxf(acc.w, v0.w), fmaxf(v1.w, v2.w)), v3.w);
        }
        for (; k < cnt; ++k) {             // tail, no duplicate loads
            unsigned int p = order[s + k];
            vf4 v = *(const vf4*)&x[(size_t)p * NCH + (size_t)cg * 4];
            acc.x = fmaxf(acc.x, v.x);
            acc.y = fmaxf(acc.y, v.y);
            acc.z = fmaxf(acc.z, v.z);
            acc.w = fmaxf(acc.w, v.w);
        }
        if (cnt == 0u) acc = (vf4)(0.0f);  // empty cell -> 0
        __builtin_nontemporal_store(
            acc, (vf4*)&out[(size_t)c * NCH + (size_t)cg * 4]);
    }
}

extern "C" void kernel_launch(void* const* d_in, const int* in_sizes, int n_in,
                              void* d_out, int out_size, void* d_ws, size_t ws_size,
                              hipStream_t stream) {
    const float* x   = (const float*)d_in[0];
    const int* pos   = (const int*)d_in[1];
    const int* batch = (const int*)d_in[2];
    float* out = (float*)d_out;
    int n = in_sizes[2];

    // workspace layout (~10 MB)
    unsigned int* counts    = (unsigned int*)d_ws;          // NSEG
    unsigned int* offsets   = counts + NSEG;                // NSEG + 1
    unsigned int* blocksum  = offsets + NSEG + 1;           // 1024
    unsigned int* blockbase = blocksum + 1024;              // 1024
    unsigned int* cellrank  = blockbase + 1024;             // N
    unsigned int* order     = cellrank + n;                 // N

    (void)hipMemsetAsync(counts, 0, (size_t)NSEG * sizeof(unsigned int), stream);

    count_kernel<<<4096, 256, 0, stream>>>(pos, batch, counts, cellrank, n);
    reduce_kernel<<<SCAN_BLOCKS, 256, 0, stream>>>(counts, blocksum);
    scanblock_kernel<<<1, 1024, 0, stream>>>(blocksum, blockbase);
    offsets_kernel<<<SCAN_BLOCKS, 256, 0, stream>>>(counts, blockbase, offsets, n);
    reorder_kernel<<<4096, 256, 0, stream>>>(cellrank, offsets, order, n);
    gather_kernel<<<2048, 256, 0, stream>>>(x, offsets, order, out);
}